// Round 1
// baseline (66.851 us; speedup 1.0000x reference)
//
#include <hip/hip_runtime.h>

#define N_SAMPLES 128

__global__ __launch_bounds__(256) void volrender_kernel(
    const float* __restrict__ depth,
    const float* __restrict__ rgb,
    const float* __restrict__ sigma,
    float* __restrict__ out_color,
    float* __restrict__ out_depth,
    int n_rays)
{
    const int lane = threadIdx.x & 63;
    const int wave = threadIdx.x >> 6;
    const int ray  = blockIdx.x * 4 + wave;
    if (ray >= n_rays) return;

    const size_t base = (size_t)ray * N_SAMPLES;

    // Each lane owns samples 2*lane and 2*lane+1.
    float2 d01 = *reinterpret_cast<const float2*>(depth + base + 2 * lane);
    float2 s01 = *reinterpret_cast<const float2*>(sigma + base + 2 * lane);

    // delta[l] = d[l+1] - d[l]; last sample padded with 1e10
    float dnext  = __shfl_down(d01.x, 1);
    float delta0 = d01.y - d01.x;
    float delta1 = (lane == 63) ? 1e10f : (dnext - d01.y);

    const float EPS = 1e-10f;
    float e0 = __expf(-fmaxf(s01.x, 0.0f) * delta0);
    float e1 = __expf(-fmaxf(s01.y, 0.0f) * delta1);
    float a0 = 1.0f - e0;
    float a1 = 1.0f - e1;
    float t0 = 1.0f - a0 + EPS;   // == e0 + EPS (match reference rounding path)
    float t1 = 1.0f - a1 + EPS;

    // Inclusive multiplicative scan across lanes of per-lane product t0*t1
    float p = t0 * t1;
#pragma unroll
    for (int off = 1; off < 64; off <<= 1) {
        float v = __shfl_up(p, off);
        if (lane >= off) p *= v;
    }
    // Exclusive product for this lane's first sample
    float excl = __shfl_up(p, 1);
    if (lane == 0) excl = 1.0f;

    float w0 = a0 * excl;
    float w1 = a1 * excl * t0;

    // rgb: samples 2l,2l+1 -> 6 contiguous floats at ray*384 + 6*lane
    const float* rbase = rgb + (size_t)ray * (N_SAMPLES * 3) + lane * 6;
    float2 r01 = *reinterpret_cast<const float2*>(rbase);      // R0 G0
    float2 r23 = *reinterpret_cast<const float2*>(rbase + 2);  // B0 R1
    float2 r45 = *reinterpret_cast<const float2*>(rbase + 4);  // G1 B1

    auto sigmoid = [](float x) { return 1.0f / (1.0f + __expf(-x)); };

    float c0 = w0 * sigmoid(r01.x) + w1 * sigmoid(r23.y);
    float c1 = w0 * sigmoid(r01.y) + w1 * sigmoid(r45.x);
    float c2 = w0 * sigmoid(r23.x) + w1 * sigmoid(r45.y);
    float dd = w0 * d01.x + w1 * d01.y;

    // Wave-wide sum of the 4 accumulators
#pragma unroll
    for (int m = 32; m >= 1; m >>= 1) {
        c0 += __shfl_xor(c0, m);
        c1 += __shfl_xor(c1, m);
        c2 += __shfl_xor(c2, m);
        dd += __shfl_xor(dd, m);
    }

    if (lane == 0) {
        out_color[(size_t)ray * 3 + 0] = c0;
        out_color[(size_t)ray * 3 + 1] = c1;
        out_color[(size_t)ray * 3 + 2] = c2;
        out_depth[ray] = dd;
    }
}

extern "C" void kernel_launch(void* const* d_in, const int* in_sizes, int n_in,
                              void* d_out, int out_size, void* d_ws, size_t ws_size,
                              hipStream_t stream)
{
    const float* depth = (const float*)d_in[0];
    const float* rgb   = (const float*)d_in[1];
    const float* sigma = (const float*)d_in[2];

    const int n_rays = in_sizes[0] / N_SAMPLES;

    float* out_color = (float*)d_out;                      // [n_rays, 3]
    float* out_depth = out_color + (size_t)n_rays * 3;     // [n_rays, 1]

    const int waves_per_block = 4;  // 256 threads
    const int blocks = (n_rays + waves_per_block - 1) / waves_per_block;

    hipLaunchKernelGGL(volrender_kernel, dim3(blocks), dim3(256), 0, stream,
                       depth, rgb, sigma, out_color, out_depth, n_rays);
}

// Round 2
// 61.438 us; speedup vs baseline: 1.0881x; 1.0881x over previous
//
#include <hip/hip_runtime.h>

#define N_SAMPLES 128

__global__ __launch_bounds__(256) void volrender_kernel(
    const float* __restrict__ depth,
    const float* __restrict__ rgb,
    const float* __restrict__ sigma,
    float* __restrict__ out_color,
    float* __restrict__ out_depth,
    int n_rays)
{
    // 32 lanes per ray, 4 samples per lane. 2 rays per wave, 8 rays per block.
    const int tid   = threadIdx.x;
    const int llane = tid & 31;               // lane within the ray's 32-lane group
    const int ray   = blockIdx.x * 8 + (tid >> 5);
    if (ray >= n_rays) return;

    const size_t base = (size_t)ray * N_SAMPLES;

    float4 d = *reinterpret_cast<const float4*>(depth + base + 4 * llane);
    float4 s = *reinterpret_cast<const float4*>(sigma + base + 4 * llane);

    // delta[i] = d[i+1] - d[i]; sample 127 padded with 1e10
    float dnext  = __shfl_down(d.x, 1, 32);
    float delta0 = d.y - d.x;
    float delta1 = d.z - d.y;
    float delta2 = d.w - d.z;
    float delta3 = (llane == 31) ? 1e10f : (dnext - d.w);

    const float EPS = 1e-10f;
    float e0 = __expf(-fmaxf(s.x, 0.0f) * delta0);
    float e1 = __expf(-fmaxf(s.y, 0.0f) * delta1);
    float e2 = __expf(-fmaxf(s.z, 0.0f) * delta2);
    float e3 = __expf(-fmaxf(s.w, 0.0f) * delta3);
    float a0 = 1.0f - e0, a1 = 1.0f - e1, a2 = 1.0f - e2, a3 = 1.0f - e3;
    float t0 = e0 + EPS, t1 = e1 + EPS, t2 = e2 + EPS, t3 = e3 + EPS;

    // Inclusive multiplicative scan of per-lane product across 32 lanes
    float p = t0 * t1 * t2 * t3;
#pragma unroll
    for (int off = 1; off < 32; off <<= 1) {
        float v = __shfl_up(p, off, 32);
        if (llane >= off) p *= v;
    }
    float excl = __shfl_up(p, 1, 32);
    if (llane == 0) excl = 1.0f;

    // Per-sample exclusive transmittance prefixes
    float w0 = a0 * excl;
    float pre1 = excl * t0;
    float w1 = a1 * pre1;
    float pre2 = pre1 * t1;
    float w2 = a2 * pre2;
    float w3 = a3 * pre2 * t2;

    // rgb: 12 contiguous floats per lane at ray*384 + 12*llane (16B-aligned)
    const float* rbase = rgb + (size_t)ray * (N_SAMPLES * 3) + llane * 12;
    float4 q0 = *reinterpret_cast<const float4*>(rbase);      // R0 G0 B0 R1
    float4 q1 = *reinterpret_cast<const float4*>(rbase + 4);  // G1 B1 R2 G2
    float4 q2 = *reinterpret_cast<const float4*>(rbase + 8);  // B2 R3 G3 B3

    auto sigmoid = [](float x) { return 1.0f / (1.0f + __expf(-x)); };

    float c0 = w0 * sigmoid(q0.x) + w1 * sigmoid(q0.w) + w2 * sigmoid(q1.z) + w3 * sigmoid(q2.y);
    float c1 = w0 * sigmoid(q0.y) + w1 * sigmoid(q1.x) + w2 * sigmoid(q1.w) + w3 * sigmoid(q2.z);
    float c2 = w0 * sigmoid(q0.z) + w1 * sigmoid(q1.y) + w2 * sigmoid(q2.x) + w3 * sigmoid(q2.w);
    float dd = w0 * d.x + w1 * d.y + w2 * d.z + w3 * d.w;

    // Reduce across the 32-lane group
#pragma unroll
    for (int m = 16; m >= 1; m >>= 1) {
        c0 += __shfl_xor(c0, m, 32);
        c1 += __shfl_xor(c1, m, 32);
        c2 += __shfl_xor(c2, m, 32);
        dd += __shfl_xor(dd, m, 32);
    }

    if (llane == 0) {
        out_color[(size_t)ray * 3 + 0] = c0;
        out_color[(size_t)ray * 3 + 1] = c1;
        out_color[(size_t)ray * 3 + 2] = c2;
        out_depth[ray] = dd;
    }
}

extern "C" void kernel_launch(void* const* d_in, const int* in_sizes, int n_in,
                              void* d_out, int out_size, void* d_ws, size_t ws_size,
                              hipStream_t stream)
{
    const float* depth = (const float*)d_in[0];
    const float* rgb   = (const float*)d_in[1];
    const float* sigma = (const float*)d_in[2];

    const int n_rays = in_sizes[0] / N_SAMPLES;

    float* out_color = (float*)d_out;                      // [n_rays, 3]
    float* out_depth = out_color + (size_t)n_rays * 3;     // [n_rays, 1]

    const int rays_per_block = 8;  // 256 threads, 32 lanes/ray
    const int blocks = (n_rays + rays_per_block - 1) / rays_per_block;

    hipLaunchKernelGGL(volrender_kernel, dim3(blocks), dim3(256), 0, stream,
                       depth, rgb, sigma, out_color, out_depth, n_rays);
}